// Round 13
// baseline (87.019 us; speedup 1.0000x reference)
//
#include <hip/hip_runtime.h>

typedef __bf16 bf16x8 __attribute__((ext_vector_type(8)));
typedef float f32x4 __attribute__((ext_vector_type(4)));
typedef unsigned short u16;

#define LSEQ 2048
#define DMODEL 1024
#define HEADD 64
#define NBATCH 8

__device__ __forceinline__ u16 cvt(float f) {
  __bf16 h = (__bf16)f;               // native v_cvt (RNE)
  return __builtin_bit_cast(u16, h);
}

// ---------------------------------------------------------------------------
// Kernel 0: pack W [1024][64] fp32 into MFMA B-FRAGMENT order (bf16):
//   wp[((p*4 + c)*32 + ks)*512 + lane*8 + j] = W_p[k = ks*32 + 8*(lane>>4) + j]
//                                                  [col = 16*c + (lane&15)]
// ---------------------------------------------------------------------------
__global__ __launch_bounds__(256) void wt_kernel(
    const float* __restrict__ Wk, const float* __restrict__ Wq,
    const float* __restrict__ Wv, u16* __restrict__ wp) {
  int idx = blockIdx.x * 256 + threadIdx.x;   // 0 .. 3*4*32*512-1 (196608)
  int j = idx & 7;
  int lane = (idx >> 3) & 63;
  int ks = (idx >> 9) & 31;
  int c = (idx >> 14) & 3;
  int p = idx >> 16;
  const float* W = (p == 0) ? Wk : ((p == 1) ? Wq : Wv);
  int k = ks * 32 + 8 * (lane >> 4) + j;
  int col = 16 * c + (lane & 15);
  wp[idx] = cvt(W[(size_t)k * HEADD + col]);
}

// ---------------------------------------------------------------------------
// Kernel 1: projections, WAVE-AUTONOMOUS (zero s_barrier in the loop).
// Block = 1 wave (64 thr) owning 16 rows x 32 output cols; A staged through
// a wave-PRIVATE 2KB LDS tile (intra-wave ds hazards only -> compiler lgkmcnt,
// no barriers; waves slip freely like the 2.3 TB/s probe). Chunk = 64 floats:
// 4 coalesced float4/lane (256B segments), reg-dbuf stgA/stgB; W-frags 1KB
// contiguous from packed panel (L2-hot). 6144 waves = 24 waves/CU
// (launch_bounds(64,6), ~70 VGPR, 2KB LDS). XCD-folded block mapping:
// rt%8 == x&7 so the h-pair (same A rows, split output cols) shares an XCD.
// p==0 -> K bf16 ; p==1 -> Q*0.125 ; p==2 -> V^T [b][64][2048]
// ---------------------------------------------------------------------------
__global__ __launch_bounds__(64, 6) void proj_kernel(
    const float* __restrict__ ik, const float* __restrict__ iq, const float* __restrict__ iv,
    const u16* __restrict__ wp, u16* __restrict__ Kb, u16* __restrict__ Qb,
    u16* __restrict__ Vt) {
  __shared__ __align__(16) u16 As[16 * 64];       // 2 KB swizzled bf16 (wave-private)
  int p = blockIdx.y;
  const float* A = (p == 0) ? ik : ((p == 1) ? iq : iv);
  const u16* Wp = wp + (size_t)p * 4 * 32 * 512;   // [c][ks_glob][512]
  int x = blockIdx.x;                 // 0..2047
  int xcd = x & 7;
  int idx = x >> 3;                   // 0..255
  int h = idx & 1;                    // output col half
  int rt = (idx >> 1) * 8 + xcd;      // row-tile 0..1023 ; rt%8 == xcd
  int lane = threadIdx.x;             // 0..63
  int l15 = lane & 15, g = lane >> 4;
  int rowbase = rt * 16;
  const float* srcbase = A + (size_t)rowbase * DMODEL;

  // staging map: piece i (0..3): row = i*4 + (lane>>4), float4-col = lane&15
  int srow = g;
  int sf4 = l15;

  float4 stgA[4], stgB[4];
  bf16x8 wfr[2][2];

  auto issue = [&](float4 (&stg)[4], int kc) {    // kc in floats
#pragma unroll
    for (int i = 0; i < 4; ++i)
      stg[i] = *(const float4*)(srcbase + (size_t)(i * 4 + srow) * DMODEL + kc + sf4 * 4);
  };
  auto commit = [&](const float4 (&stg)[4]) {
    char* base = (char*)As;
#pragma unroll
    for (int i = 0; i < 4; ++i) {
      int row = i * 4 + srow;
      ushort4 pk;
      pk.x = cvt(stg[i].x); pk.y = cvt(stg[i].y);
      pk.z = cvt(stg[i].z); pk.w = cvt(stg[i].w);
      int byte = row * 128 + ((sf4 * 8) ^ ((row & 7) << 4));
      *(ushort4*)(base + byte) = pk;
    }
  };
  auto wload = [&](int c16) {                     // chunk 0..15 (2 ks each)
#pragma unroll
    for (int ks2 = 0; ks2 < 2; ++ks2)
#pragma unroll
      for (int cc = 0; cc < 2; ++cc)
        wfr[ks2][cc] = *(const bf16x8*)(
            Wp + ((size_t)(h * 2 + cc) * 32 + c16 * 2 + ks2) * 512 + lane * 8);
  };

  f32x4 acc[2] = {};  // [cc]: row = rowbase+4g+r, col = 16*(2h+cc)+l15
  int aswz = (l15 & 7) << 4;
  auto computeC = [&]() {
#pragma unroll
    for (int ks2 = 0; ks2 < 2; ++ks2) {
      bf16x8 af = *(const bf16x8*)((const char*)As + l15 * 128 + ((ks2 * 64 + 16 * g) ^ aswz));
#pragma unroll
      for (int cc = 0; cc < 2; ++cc)
        acc[cc] = __builtin_amdgcn_mfma_f32_16x16x32_bf16(af, wfr[ks2][cc], acc[cc], 0, 0, 0);
    }
  };

  issue(stgA, 0);
#pragma unroll 1
  for (int c = 0; c < 16; c += 2) {
    // chunk c
    wload(c);                               // L2 loads (behind stgA in FIFO)
    if (c < 15) issue(stgB, (c + 1) * 64);  // next chunk HBM loads (youngest)
    commit(stgA);                           // waits stgA only (oldest)
    computeC();                             // lgkm + W waits; stgB in flight
    // chunk c+1
    wload(c + 1);
    if (c < 14) issue(stgA, (c + 2) * 64);
    commit(stgB);
    computeC();
  }

  if (p == 2) {
    // store V transposed: Vt[b][d][tok], pack 4 consecutive tokens -> 8B store
    int row0 = rowbase + 4 * g;
    int b = row0 >> 11, tok = row0 & 2047;
#pragma unroll
    for (int cc = 0; cc < 2; ++cc) {
      int d = 16 * (2 * h + cc) + l15;
      ushort4 pk;
      pk.x = cvt(acc[cc][0]); pk.y = cvt(acc[cc][1]);
      pk.z = cvt(acc[cc][2]); pk.w = cvt(acc[cc][3]);
      *(ushort4*)(Vt + ((size_t)b * HEADD + d) * LSEQ + tok) = pk;
    }
  } else {
    u16* dst = (p == 0) ? Kb : Qb;
    float s = (p == 1) ? 0.125f : 1.0f;  // fold softmax scale into Q (exact pow2)
#pragma unroll
    for (int cc = 0; cc < 2; ++cc)
#pragma unroll
      for (int r = 0; r < 4; ++r)
        dst[(size_t)(rowbase + 4 * g + r) * HEADD + 16 * (2 * h + cc) + l15] =
            cvt(acc[cc][r] * s);
  }
}

// ---------------------------------------------------------------------------
// Kernel 2: causal flash attention, split-K + XCD-aware swizzle (unchanged;
// ~2-3us after R11's swizzle made K/Q/V L2-resident per XCD).
// ---------------------------------------------------------------------------
__global__ __launch_bounds__(128) void attn_kernel(
    const u16* __restrict__ Kb, const u16* __restrict__ Qb, const u16* __restrict__ Vt,
    float* __restrict__ out) {
  __shared__ __align__(16) u16 plds[2][16 * 40];  // per-wave P tile [16q][32k]
  __shared__ __align__(16) float mrg[64][18];     // wave1: acc16 + m + l
  int lane = threadIdx.x & 63;
  int wv = threadIdx.x >> 6;
  int l15 = lane & 15, g = lane >> 4;
  int id = blockIdx.x;                    // 0..1023
  int b = id & 7;                         // XCD-aligned batch
  int qt = 127 - (id >> 3);               // heavy q-tiles first
  int qbase = qt * 16;                    // within batch (16 rows per block)

  const u16* Qp = Qb + ((size_t)b * LSEQ + qbase) * HEADD;
  const u16* Kp = Kb + (size_t)b * LSEQ * HEADD;
  const u16* Vp = Vt + (size_t)b * HEADD * LSEQ;

  bf16x8 qf[2];
#pragma unroll
  for (int ds = 0; ds < 2; ++ds)
    qf[ds] = *(const bf16x8*)(Qp + (size_t)l15 * HEADD + 32 * ds + 8 * g);

  f32x4 acc[4] = {};        // [c]: reg r -> q-row qbase+4g+r, col d=16c+l15
  float m = -1e30f, lsum = 0.f;
  int q_abs = qbase + l15;
  int ntiles = (qbase + 47) >> 5;

  for (int t = wv; t < ntiles; t += 2) {
    int kbase = t * 32;
    f32x4 sacc[2] = {};     // [f]: key = kbase+16f+4g+r, q = qbase+l15
#pragma unroll
    for (int f = 0; f < 2; ++f)
#pragma unroll
      for (int ds = 0; ds < 2; ++ds) {
        bf16x8 kf = *(const bf16x8*)(Kp + (size_t)(kbase + 16 * f + l15) * HEADD + 32 * ds + 8 * g);
        sacc[f] = __builtin_amdgcn_mfma_f32_16x16x32_bf16(kf, qf[ds], sacc[f], 0, 0, 0);
      }

    // causal mask + row-max (row == this lane's q)
    float sv[2][4];
    float tmax = -1e30f;
#pragma unroll
    for (int f = 0; f < 2; ++f)
#pragma unroll
      for (int r = 0; r < 4; ++r) {
        int key = kbase + 16 * f + 4 * g + r;
        float s = (key <= q_abs) ? sacc[f][r] : -1e30f;
        sv[f][r] = s;
        tmax = fmaxf(tmax, s);
      }
    tmax = fmaxf(tmax, __shfl_xor(tmax, 16));
    tmax = fmaxf(tmax, __shfl_xor(tmax, 32));
    float mnew = fmaxf(m, tmax);
    float al = __expf(m - mnew);
    float pv[2][4];
    float rs = 0.f;
#pragma unroll
    for (int f = 0; f < 2; ++f)
#pragma unroll
      for (int r = 0; r < 4; ++r) {
        pv[f][r] = __expf(sv[f][r] - mnew);
        rs += pv[f][r];
      }
    rs += __shfl_xor(rs, 16);
    rs += __shfl_xor(rs, 32);
    lsum = lsum * al + rs;
    m = mnew;

    // rescale O accumulator: row 4g+r's factor lives at lane (4g+r)
    float alr[4];
#pragma unroll
    for (int r = 0; r < 4; ++r) alr[r] = __shfl(al, 4 * g + r);
#pragma unroll
    for (int c = 0; c < 4; ++c)
#pragma unroll
      for (int r = 0; r < 4; ++r) acc[c][r] *= alr[r];

    // P -> LDS in PV A-frag layout: P[q=l15][key 16f+4g + r]
#pragma unroll
    for (int f = 0; f < 2; ++f) {
      ushort4 pk;
      pk.x = cvt(pv[f][0]); pk.y = cvt(pv[f][1]);
      pk.z = cvt(pv[f][2]); pk.w = cvt(pv[f][3]);
      *(ushort4*)&plds[wv][l15 * 40 + 16 * f + 4 * g] = pk;
    }
    bf16x8 ap = *(const bf16x8*)&plds[wv][l15 * 40 + 8 * g];

    // PV: B-frag = V[kbase+8g+j][16c+l15] = Vt[16c+l15][kbase+8g+j]
#pragma unroll
    for (int c = 0; c < 4; ++c) {
      bf16x8 vf = *(const bf16x8*)(Vp + (size_t)(16 * c + l15) * LSEQ + kbase + 8 * g);
      acc[c] = __builtin_amdgcn_mfma_f32_16x16x32_bf16(ap, vf, acc[c], 0, 0, 0);
    }
  }

  // ---- split-K merge: wave1 publishes, wave0 combines + stores ----
  if (wv == 1) {
#pragma unroll
    for (int c = 0; c < 4; ++c)
#pragma unroll
      for (int r = 0; r < 4; ++r) mrg[lane][c * 4 + r] = acc[c][r];
    mrg[lane][16] = m;
    mrg[lane][17] = lsum;
  }
  __syncthreads();
  if (wv == 0) {
    float m1 = mrg[lane][16], l1 = mrg[lane][17];
    float mT = fmaxf(m, m1);
    float e0 = __expf(m - mT), e1 = __expf(m1 - mT);  // empty wave1: e1 = 0
    float lT = lsum * e0 + l1 * e1;
    float e0r[4], e1r[4], li[4];
#pragma unroll
    for (int r = 0; r < 4; ++r) {
      e0r[r] = __shfl(e0, 4 * g + r);
      e1r[r] = __shfl(e1, 4 * g + r);
      li[r] = 1.0f / __shfl(lT, 4 * g + r);
    }
#pragma unroll
    for (int c = 0; c < 4; ++c)
#pragma unroll
      for (int r = 0; r < 4; ++r) {
        float v = acc[c][r] * e0r[r] + mrg[lane][c * 4 + r] * e1r[r];
        out[((size_t)b * LSEQ + qbase + 4 * g + r) * HEADD + 16 * c + l15] = v * li[r];
      }
  }
}

// ---------------------------------------------------------------------------
extern "C" void kernel_launch(void* const* d_in, const int* in_sizes, int n_in,
                              void* d_out, int out_size, void* d_ws, size_t ws_size,
                              hipStream_t stream) {
  const float* idx_k = (const float*)d_in[0];
  const float* idx_q = (const float*)d_in[1];
  const float* idx_v = (const float*)d_in[2];
  // d_in[3] = msk : causal mask is applied analytically, never read
  const float* Wk = (const float*)d_in[4];
  const float* Wq = (const float*)d_in[5];
  const float* Wv = (const float*)d_in[6];
  float* out = (float*)d_out;

  char* ws = (char*)d_ws;
  const size_t WT_BYTES = (size_t)3 * 4 * 32 * 512 * 2;          // 384 KB packed W
  const size_t MAT_BYTES = (size_t)NBATCH * LSEQ * HEADD * 2;    // 2 MB each
  u16* wp = (u16*)ws;
  u16* Kb = (u16*)(ws + WT_BYTES);
  u16* Qb = (u16*)(ws + WT_BYTES + MAT_BYTES);
  u16* Vt = (u16*)(ws + WT_BYTES + 2 * MAT_BYTES);

  hipLaunchKernelGGL(wt_kernel, dim3(768), dim3(256), 0, stream, Wk, Wq, Wv, wp);
  hipLaunchKernelGGL(proj_kernel, dim3(2048, 3), dim3(64), 0, stream,
                     idx_k, idx_q, idx_v, wp, Kb, Qb, Vt);
  hipLaunchKernelGGL(attn_kernel, dim3(1024), dim3(128), 0, stream, Kb, Qb, Vt, out);
}

// Round 14
// 83.474 us; speedup vs baseline: 1.0425x; 1.0425x over previous
//
#include <hip/hip_runtime.h>

typedef __bf16 bf16x8 __attribute__((ext_vector_type(8)));
typedef float f32x4 __attribute__((ext_vector_type(4)));
typedef unsigned short u16;

#define LSEQ 2048
#define DMODEL 1024
#define HEADD 64
#define NBATCH 8

__device__ __forceinline__ u16 cvt(float f) {
  __bf16 h = (__bf16)f;               // native v_cvt (RNE)
  return __builtin_bit_cast(u16, h);
}

// Raw workgroup barrier draining ONLY LDS counters: in-flight global loads
// (the 2-deep A prefetch) survive the barrier.
#define BARRIER_LGKM() do {                                   \
    asm volatile("s_waitcnt lgkmcnt(0)" ::: "memory");        \
    __builtin_amdgcn_sched_barrier(0);                        \
    __builtin_amdgcn_s_barrier();                             \
    __builtin_amdgcn_sched_barrier(0);                        \
  } while (0)

// ---------------------------------------------------------------------------
// Kernel 0: pack W [1024][64] fp32 into MFMA B-FRAGMENT order (bf16):
//   wp[((p*4 + c)*32 + ks)*512 + lane*8 + j] = W_p[k = ks*32 + 8*(lane>>4) + j]
//                                                  [col = 16*c + (lane&15)]
// ---------------------------------------------------------------------------
__global__ __launch_bounds__(256) void wt_kernel(
    const float* __restrict__ Wk, const float* __restrict__ Wq,
    const float* __restrict__ Wv, u16* __restrict__ wp) {
  int idx = blockIdx.x * 256 + threadIdx.x;   // 0 .. 3*4*32*512-1 (196608)
  int j = idx & 7;
  int lane = (idx >> 3) & 63;
  int ks = (idx >> 9) & 31;
  int c = (idx >> 14) & 3;
  int p = idx >> 16;
  const float* W = (p == 0) ? Wk : ((p == 1) ? Wq : Wv);
  int k = ks * 32 + 8 * (lane >> 4) + j;
  int col = 16 * c + (lane & 15);
  wp[idx] = cvt(W[(size_t)k * HEADD + col]);
}

// ---------------------------------------------------------------------------
// Kernel 1: projections — EXACT R10 structure (best measured: 70.8-75.9us).
// Block 256 thr / 4 waves / 64 rows; K chunked by 128 (8 chunks).
// LDS: A dbuf 2x16KB XOR-swizzled (32 KB). Per chunk: W-frags (L2, 1KB
// contiguous) load FIRST (oldest in vmcnt FIFO), then issue A for chunk+2
// (youngest, in flight >=2 compute phases), compute waits counted vmcnt only,
// commit writes chunk+1's staged regs to LDS, lgkm-only barrier.
// p==0 -> K bf16 ; p==1 -> Q*0.125 ; p==2 -> V^T [b][64][2048]
// ---------------------------------------------------------------------------
__global__ __launch_bounds__(256) void proj_kernel(
    const float* __restrict__ ik, const float* __restrict__ iq, const float* __restrict__ iv,
    const u16* __restrict__ wp, u16* __restrict__ Kb, u16* __restrict__ Qb,
    u16* __restrict__ Vt) {
  __shared__ __align__(16) u16 Asw[2][64 * 128];  // 2 x 16 KB swizzled bf16
  int p = blockIdx.y;
  const float* A = (p == 0) ? ik : ((p == 1) ? iq : iv);
  const u16* Wp = wp + (size_t)p * 4 * 32 * 512;   // [c][ks_glob][512]
  int t = threadIdx.x;
  int lane = t & 63;
  int wv = t >> 6;
  int l15 = lane & 15, g = lane >> 4;
  int rowbase = blockIdx.x * 64;
  const float* srcbase = A + (size_t)rowbase * DMODEL;

  // A staging map: piece i (0..7): row = i*8 + (t>>5), float-col = (t&31)*4
  int srow0 = t >> 5;
  int scol = (t & 31) * 4;

  float4 stgA[8], stgB[8];
  bf16x8 wfr[4][4];

  auto issue = [&](float4 (&stg)[8], int kc) {
#pragma unroll
    for (int i = 0; i < 8; ++i)
      stg[i] = *(const float4*)(srcbase + (size_t)(i * 8 + srow0) * DMODEL + kc + scol);
  };
  auto commit = [&](const float4 (&stg)[8], u16* basep) {
    char* base = (char*)basep;
#pragma unroll
    for (int i = 0; i < 8; ++i) {
      int row = i * 8 + srow0;
      ushort4 pk;
      pk.x = cvt(stg[i].x); pk.y = cvt(stg[i].y);
      pk.z = cvt(stg[i].z); pk.w = cvt(stg[i].w);
      int byte = row * 256 + ((scol * 2) ^ ((row & 7) << 4));
      *(ushort4*)(base + byte) = pk;
    }
  };
  auto wload = [&](int c8) {
#pragma unroll
    for (int ks = 0; ks < 4; ++ks)
#pragma unroll
      for (int c = 0; c < 4; ++c)
        wfr[ks][c] = *(const bf16x8*)(Wp + ((size_t)c * 32 + c8 * 4 + ks) * 512 + lane * 8);
  };

  f32x4 acc[4] = {};  // [c]: row = rowbase+16wv+4g+r, col = 16c+l15
  int abase = (16 * wv + l15) * 256;
  int aswz = (l15 & 7) << 4;

  auto computeC = [&](const char* lbase) {
#pragma unroll
    for (int ks = 0; ks < 4; ++ks) {
      bf16x8 af = *(const bf16x8*)(lbase + abase + ((ks * 64 + 16 * g) ^ aswz));
#pragma unroll
      for (int c = 0; c < 4; ++c)
        acc[c] = __builtin_amdgcn_mfma_f32_16x16x32_bf16(af, wfr[ks][c], acc[c], 0, 0, 0);
    }
  };

  // prologue: stgA=kc0, stgB=kc1; commit kc0; barrier
  issue(stgA, 0);
  issue(stgB, 128);
  commit(stgA, &Asw[0][0]);
  BARRIER_LGKM();

#pragma unroll 1
  for (int cc = 0; cc < 8; cc += 2) {
    // ---- even chunk c8 = cc : compute buf0 ----
    wload(cc);                                   // oldest in vmcnt queue
    __builtin_amdgcn_sched_barrier(0);
    if (cc < 6) issue(stgA, (cc + 2) * 128);     // youngest: in flight 2 phases
    __builtin_amdgcn_sched_barrier(0);
    computeC((const char*)&Asw[0][0]);
    commit(stgB, &Asw[1][0]);                    // kc = cc+1 (landed long ago)
    BARRIER_LGKM();
    // ---- odd chunk c8 = cc+1 : compute buf1 ----
    wload(cc + 1);
    __builtin_amdgcn_sched_barrier(0);
    if (cc < 5) issue(stgB, (cc + 3) * 128);
    __builtin_amdgcn_sched_barrier(0);
    computeC((const char*)&Asw[1][0]);
    if (cc < 6) commit(stgA, &Asw[0][0]);        // kc = cc+2
    BARRIER_LGKM();
  }

  int rb2 = rowbase + 16 * wv;
  if (p == 2) {
    // store V transposed: Vt[b][d][tok], pack 4 consecutive tokens -> 8B store
    int row0 = rb2 + 4 * g;
    int b = row0 >> 11, tok = row0 & 2047;
#pragma unroll
    for (int c = 0; c < 4; ++c) {
      int d = 16 * c + l15;
      ushort4 pk;
      pk.x = cvt(acc[c][0]); pk.y = cvt(acc[c][1]);
      pk.z = cvt(acc[c][2]); pk.w = cvt(acc[c][3]);
      *(ushort4*)(Vt + ((size_t)b * HEADD + d) * LSEQ + tok) = pk;
    }
  } else {
    u16* dst = (p == 0) ? Kb : Qb;
    float s = (p == 1) ? 0.125f : 1.0f;  // fold softmax scale into Q (exact pow2)
#pragma unroll
    for (int c = 0; c < 4; ++c)
#pragma unroll
      for (int r = 0; r < 4; ++r)
        dst[(size_t)(rb2 + 4 * g + r) * HEADD + 16 * c + l15] = cvt(acc[c][r] * s);
  }
}

// ---------------------------------------------------------------------------
// Kernel 2: causal flash attention, split-K + XCD-aware swizzle (R11 version;
// ~3us: b = id&7 pins each batch to one XCD -> K/Q/V L2-resident).
// ---------------------------------------------------------------------------
__global__ __launch_bounds__(128) void attn_kernel(
    const u16* __restrict__ Kb, const u16* __restrict__ Qb, const u16* __restrict__ Vt,
    float* __restrict__ out) {
  __shared__ __align__(16) u16 plds[2][16 * 40];  // per-wave P tile [16q][32k]
  __shared__ __align__(16) float mrg[64][18];     // wave1: acc16 + m + l
  int lane = threadIdx.x & 63;
  int wv = threadIdx.x >> 6;
  int l15 = lane & 15, g = lane >> 4;
  int id = blockIdx.x;                    // 0..1023
  int b = id & 7;                         // XCD-aligned batch
  int qt = 127 - (id >> 3);               // heavy q-tiles first
  int qbase = qt * 16;                    // within batch (16 rows per block)

  const u16* Qp = Qb + ((size_t)b * LSEQ + qbase) * HEADD;
  const u16* Kp = Kb + (size_t)b * LSEQ * HEADD;
  const u16* Vp = Vt + (size_t)b * HEADD * LSEQ;

  bf16x8 qf[2];
#pragma unroll
  for (int ds = 0; ds < 2; ++ds)
    qf[ds] = *(const bf16x8*)(Qp + (size_t)l15 * HEADD + 32 * ds + 8 * g);

  f32x4 acc[4] = {};        // [c]: reg r -> q-row qbase+4g+r, col d=16c+l15
  float m = -1e30f, lsum = 0.f;
  int q_abs = qbase + l15;
  int ntiles = (qbase + 47) >> 5;

  for (int t = wv; t < ntiles; t += 2) {
    int kbase = t * 32;
    f32x4 sacc[2] = {};     // [f]: key = kbase+16f+4g+r, q = qbase+l15
#pragma unroll
    for (int f = 0; f < 2; ++f)
#pragma unroll
      for (int ds = 0; ds < 2; ++ds) {
        bf16x8 kf = *(const bf16x8*)(Kp + (size_t)(kbase + 16 * f + l15) * HEADD + 32 * ds + 8 * g);
        sacc[f] = __builtin_amdgcn_mfma_f32_16x16x32_bf16(kf, qf[ds], sacc[f], 0, 0, 0);
      }

    // causal mask + row-max (row == this lane's q)
    float sv[2][4];
    float tmax = -1e30f;
#pragma unroll
    for (int f = 0; f < 2; ++f)
#pragma unroll
      for (int r = 0; r < 4; ++r) {
        int key = kbase + 16 * f + 4 * g + r;
        float s = (key <= q_abs) ? sacc[f][r] : -1e30f;
        sv[f][r] = s;
        tmax = fmaxf(tmax, s);
      }
    tmax = fmaxf(tmax, __shfl_xor(tmax, 16));
    tmax = fmaxf(tmax, __shfl_xor(tmax, 32));
    float mnew = fmaxf(m, tmax);
    float al = __expf(m - mnew);
    float pv[2][4];
    float rs = 0.f;
#pragma unroll
    for (int f = 0; f < 2; ++f)
#pragma unroll
      for (int r = 0; r < 4; ++r) {
        pv[f][r] = __expf(sv[f][r] - mnew);
        rs += pv[f][r];
      }
    rs += __shfl_xor(rs, 16);
    rs += __shfl_xor(rs, 32);
    lsum = lsum * al + rs;
    m = mnew;

    // rescale O accumulator: row 4g+r's factor lives at lane (4g+r)
    float alr[4];
#pragma unroll
    for (int r = 0; r < 4; ++r) alr[r] = __shfl(al, 4 * g + r);
#pragma unroll
    for (int c = 0; c < 4; ++c)
#pragma unroll
      for (int r = 0; r < 4; ++r) acc[c][r] *= alr[r];

    // P -> LDS in PV A-frag layout: P[q=l15][key 16f+4g + r]
#pragma unroll
    for (int f = 0; f < 2; ++f) {
      ushort4 pk;
      pk.x = cvt(pv[f][0]); pk.y = cvt(pv[f][1]);
      pk.z = cvt(pv[f][2]); pk.w = cvt(pv[f][3]);
      *(ushort4*)&plds[wv][l15 * 40 + 16 * f + 4 * g] = pk;
    }
    bf16x8 ap = *(const bf16x8*)&plds[wv][l15 * 40 + 8 * g];

    // PV: B-frag = V[kbase+8g+j][16c+l15] = Vt[16c+l15][kbase+8g+j]
#pragma unroll
    for (int c = 0; c < 4; ++c) {
      bf16x8 vf = *(const bf16x8*)(Vp + (size_t)(16 * c + l15) * LSEQ + kbase + 8 * g);
      acc[c] = __builtin_amdgcn_mfma_f32_16x16x32_bf16(ap, vf, acc[c], 0, 0, 0);
    }
  }

  // ---- split-K merge: wave1 publishes, wave0 combines + stores ----
  if (wv == 1) {
#pragma unroll
    for (int c = 0; c < 4; ++c)
#pragma unroll
      for (int r = 0; r < 4; ++r) mrg[lane][c * 4 + r] = acc[c][r];
    mrg[lane][16] = m;
    mrg[lane][17] = lsum;
  }
  __syncthreads();
  if (wv == 0) {
    float m1 = mrg[lane][16], l1 = mrg[lane][17];
    float mT = fmaxf(m, m1);
    float e0 = __expf(m - mT), e1 = __expf(m1 - mT);  // empty wave1: e1 = 0
    float lT = lsum * e0 + l1 * e1;
    float e0r[4], e1r[4], li[4];
#pragma unroll
    for (int r = 0; r < 4; ++r) {
      e0r[r] = __shfl(e0, 4 * g + r);
      e1r[r] = __shfl(e1, 4 * g + r);
      li[r] = 1.0f / __shfl(lT, 4 * g + r);
    }
#pragma unroll
    for (int c = 0; c < 4; ++c)
#pragma unroll
      for (int r = 0; r < 4; ++r) {
        float v = acc[c][r] * e0r[r] + mrg[lane][c * 4 + r] * e1r[r];
        out[((size_t)b * LSEQ + qbase + 4 * g + r) * HEADD + 16 * c + l15] = v * li[r];
      }
  }
}

// ---------------------------------------------------------------------------
extern "C" void kernel_launch(void* const* d_in, const int* in_sizes, int n_in,
                              void* d_out, int out_size, void* d_ws, size_t ws_size,
                              hipStream_t stream) {
  const float* idx_k = (const float*)d_in[0];
  const float* idx_q = (const float*)d_in[1];
  const float* idx_v = (const float*)d_in[2];
  // d_in[3] = msk : causal mask is applied analytically, never read
  const float* Wk = (const float*)d_in[4];
  const float* Wq = (const float*)d_in[5];
  const float* Wv = (const float*)d_in[6];
  float* out = (float*)d_out;

  char* ws = (char*)d_ws;
  const size_t WT_BYTES = (size_t)3 * 4 * 32 * 512 * 2;          // 384 KB packed W
  const size_t MAT_BYTES = (size_t)NBATCH * LSEQ * HEADD * 2;    // 2 MB each
  u16* wp = (u16*)ws;
  u16* Kb = (u16*)(ws + WT_BYTES);
  u16* Qb = (u16*)(ws + WT_BYTES + MAT_BYTES);
  u16* Vt = (u16*)(ws + WT_BYTES + 2 * MAT_BYTES);

  hipLaunchKernelGGL(wt_kernel, dim3(768), dim3(256), 0, stream, Wk, Wq, Wv, wp);
  hipLaunchKernelGGL(proj_kernel, dim3(256, 3), dim3(256), 0, stream,
                     idx_k, idx_q, idx_v, wp, Kb, Qb, Vt);
  hipLaunchKernelGGL(attn_kernel, dim3(1024), dim3(128), 0, stream, Kb, Qb, Vt, out);
}